// Round 4
// baseline (346.627 us; speedup 1.0000x reference)
//
#include <hip/hip_runtime.h>
#include <cstdint>

// Top-k (k=384) along last axis (C=768) of [B=16, N=4096, C=768] fp32, scatter
// values back, zeros elsewhere. One wave (64 lanes) per row-group, 4 waves/block.
//
// v3b: fix compile error — __builtin_nontemporal_load/store rejects HIP's
// struct-based uint4/float4; use native ext_vector_type(4) typedefs instead.
// Logic unchanged from v3: software-pipeline 8 rows per wave (convert row i ->
// issue row i+1 loads -> search/store row i), keeping HBM loads in flight
// under the serial ballot bit-search. Nontemporal hints (zero-reuse 402MB
// stream > L3). Zero LDS / atomics / barriers. Exact select, tie-break =
// lowest index (matches jax.lax.top_k).

constexpr int C   = 768;
constexpr int TPB = 256;
constexpr int WPB = TPB / 64;  // 4 waves per block
constexpr int EPL = C / 64;    // 12 elements per lane
constexpr int NV  = EPL / 4;   // 3 16B loads per lane
constexpr int RPW = 8;         // rows per wave (pipeline depth-2 over rows)

typedef uint32_t uint4v  __attribute__((ext_vector_type(4)));  // native vec — OK for nontemporal builtins
typedef float    float4v __attribute__((ext_vector_type(4)));

// Monotone bijection fp32 bits -> uint32 (larger float => larger key), then
// xor with flip (~0 for largest=0 so "largest key" = smallest float).
__device__ __forceinline__ uint32_t f2key(uint32_t b, uint32_t flip) {
    uint32_t m = (uint32_t)((int32_t)b >> 31) | 0x80000000u; // neg: ~b, pos: b|0x8000...
    return (b ^ m) ^ flip;
}
__device__ __forceinline__ float key2f(uint32_t key, uint32_t flip) {
    uint32_t u = key ^ flip;
    uint32_t m = (~(uint32_t)((int32_t)u >> 31)) | 0x80000000u;
    return __uint_as_float(u ^ m);
}

__global__ __launch_bounds__(TPB, 8) void topk_scatter_row(
        const float* __restrict__ x,
        const int*   __restrict__ pk,
        const int*   __restrict__ plg,
        float*       __restrict__ out,
        int rows) {
    const int lane = threadIdx.x & 63;
    const int wid  = threadIdx.x >> 6;
    const int row0 = (blockIdx.x * WPB + wid) * RPW;
    if (row0 >= rows) return;

    const int      k    = pk[0];
    const uint32_t flip = (plg[0] != 0) ? 0u : 0xFFFFFFFFu;

    const uint4v* xv = (const uint4v*)(x + (size_t)row0 * C); // row = 192 vec4
    const int nrow = (rows - row0 < RPW) ? (rows - row0) : RPW;

    // prologue: load first row (element e=j*4+c at row idx j*256+lane*4+c)
    uint4v pre[NV];
    #pragma unroll
    for (int j = 0; j < NV; ++j)
        pre[j] = __builtin_nontemporal_load(&xv[j * 64 + lane]);

    for (int i = 0; i < nrow; ++i) {
        // ---- keys for current row (consumes pre) --------------------------
        uint32_t key[EPL];
        #pragma unroll
        for (int j = 0; j < NV; ++j) {
            #pragma unroll
            for (int c2 = 0; c2 < 4; ++c2)
                key[j*4+c2] = f2key(pre[j][c2], flip);
        }
        // ---- prefetch next row: in flight during the search ---------------
        if (i + 1 < nrow) {
            const uint4v* xn = xv + (size_t)(i + 1) * (C / 4);
            #pragma unroll
            for (int j = 0; j < NV; ++j)
                pre[j] = __builtin_nontemporal_load(&xn[j * 64 + lane]);
        }

        float4v* orow = (float4v*)(out + (size_t)(row0 + i) * C);

        if (k <= 0) {
            const float4v z = {0.f, 0.f, 0.f, 0.f};
            #pragma unroll
            for (int j = 0; j < NV; ++j)
                __builtin_nontemporal_store(z, &orow[j * 64 + lane]);
            continue;
        }
        if (k >= C) {   // select everything
            #pragma unroll
            for (int j = 0; j < NV; ++j) {
                float4v o;
                #pragma unroll
                for (int c2 = 0; c2 < 4; ++c2) o[c2] = key2f(key[j*4+c2], flip);
                __builtin_nontemporal_store(o, &orow[j * 64 + lane]);
            }
            continue;
        }

        // ---- bitwise binary search for T = k-th largest key ---------------
        // Invariant: count(key >= T) >= k.
        uint32_t T = 0;
        bool exact = false;
        for (int b = 31; b >= 0; --b) {
            const uint32_t cand = T | (1u << b);
            int cnt = 0;
            #pragma unroll
            for (int e = 0; e < EPL; ++e)
                cnt += __popcll(__ballot(key[e] >= cand));
            if (cnt >= k) {
                T = cand;
                if (cnt == k) { exact = true; break; }
            }
        }

        // ---- selection mask ----------------------------------------------
        uint32_t selmask = 0;
        if (exact) {
            #pragma unroll
            for (int e = 0; e < EPL; ++e)
                if (key[e] >= T) selmask |= 1u << e;
        } else {
            // duplicates of T straddle the boundary: take (k - count(>T)) of
            // the keys == T, lowest row-index first. Index order = (j,lane,c).
            int cgt = 0;
            #pragma unroll
            for (int e = 0; e < EPL; ++e) {
                if (key[e] > T) selmask |= 1u << e;
                cgt += __popcll(__ballot(key[e] > T));
            }
            const int need = k - cgt;  // >= 1 by construction
            const unsigned long long below = (1ull << lane) - 1ull;
            int base = 0;
            #pragma unroll
            for (int j = 0; j < NV; ++j) {
                int eq[4]; unsigned long long m[4];
                #pragma unroll
                for (int c2 = 0; c2 < 4; ++c2) {
                    eq[c2] = (key[j*4+c2] == T) ? 1 : 0;
                    m[c2]  = __ballot(eq[c2] != 0);
                }
                int lanebelow = 0;
                #pragma unroll
                for (int c2 = 0; c2 < 4; ++c2) lanebelow += __popcll(m[c2] & below);
                int own = 0;
                #pragma unroll
                for (int c2 = 0; c2 < 4; ++c2) {
                    if (eq[c2] && (base + lanebelow + own) < need)
                        selmask |= 1u << (j*4 + c2);
                    own += eq[c2];
                }
                #pragma unroll
                for (int c2 = 0; c2 < 4; ++c2) base += __popcll(m[c2]);
            }
        }

        // ---- scatter values / zeros (coalesced 16B, nontemporal) ----------
        #pragma unroll
        for (int j = 0; j < NV; ++j) {
            float4v o;
            #pragma unroll
            for (int c2 = 0; c2 < 4; ++c2) {
                const int e = j*4 + c2;
                o[c2] = ((selmask >> e) & 1u) ? key2f(key[e], flip) : 0.0f;
            }
            __builtin_nontemporal_store(o, &orow[j * 64 + lane]);
        }
    }
}

extern "C" void kernel_launch(void* const* d_in, const int* in_sizes, int n_in,
                              void* d_out, int out_size, void* d_ws, size_t ws_size,
                              hipStream_t stream) {
    const float* x   = (const float*)d_in[0];
    const int*   pk  = (const int*)d_in[1];
    const int*   plg = (const int*)d_in[2];
    float*       out = (float*)d_out;

    const int rows      = in_sizes[0] / C;              // 16*4096 = 65536
    const int rows_blk  = WPB * RPW;                    // 32 rows per block
    const int blocks    = (rows + rows_blk - 1) / rows_blk;  // 2048
    topk_scatter_row<<<blocks, TPB, 0, stream>>>(x, pk, plg, out, rows);
}

// Round 5
// 342.453 us; speedup vs baseline: 1.0122x; 1.0122x over previous
//
#include <hip/hip_runtime.h>
#include <cstdint>

// Top-k (k=384) along last axis (C=768) of [B=16, N=4096, C=768] fp32, scatter
// values back, zeros elsewhere. One wave (64 lanes) per row; grid-stride rows.
//
// v4: isolate the software-pipeline idea from v3b's two confounds.
//   - v3b bundled {pipeline, nontemporal hints, __launch_bounds__(256,8)}.
//     bounds-8 caps VGPR at 64 with ~24 live data regs (spill risk); NT
//     bypasses the L2 write path the 6.7 TB/s harness fills use. It regressed
//     (topk ~92 -> ~105us). This version keeps ONLY the pipeline:
//   - 16384 waves grid-stride over 65536 rows (4 rows/wave, stride nwaves):
//     single resident generation (no block refill bubbles), prefetch row i+1
//     issued before row i's serial ballot bit-search -> VMEM stays busy.
//   - plain loads/stores, default launch bounds (no VGPR cap).
// Zero LDS / atomics / barriers. Exact select, tie-break = lowest index
// (matches jax.lax.top_k). Search/tie/select logic identical to validated v2.

constexpr int C   = 768;
constexpr int TPB = 256;
constexpr int WPB = TPB / 64;  // 4 waves per block
constexpr int EPL = C / 64;    // 12 elements per lane
constexpr int NV  = EPL / 4;   // 3 16B loads per lane

typedef uint32_t uint4v  __attribute__((ext_vector_type(4)));
typedef float    float4v __attribute__((ext_vector_type(4)));

// Monotone bijection fp32 bits -> uint32 (larger float => larger key), then
// xor with flip (~0 for largest=0 so "largest key" = smallest float).
__device__ __forceinline__ uint32_t f2key(uint32_t b, uint32_t flip) {
    uint32_t m = (uint32_t)((int32_t)b >> 31) | 0x80000000u; // neg: ~b, pos: b|0x8000...
    return (b ^ m) ^ flip;
}
__device__ __forceinline__ float key2f(uint32_t key, uint32_t flip) {
    uint32_t u = key ^ flip;
    uint32_t m = (~(uint32_t)((int32_t)u >> 31)) | 0x80000000u;
    return __uint_as_float(u ^ m);
}

__global__ __launch_bounds__(TPB) void topk_scatter_row(
        const float* __restrict__ x,
        const int*   __restrict__ pk,
        const int*   __restrict__ plg,
        float*       __restrict__ out,
        int rows) {
    const int lane   = threadIdx.x & 63;
    const int wave   = blockIdx.x * WPB + (threadIdx.x >> 6);
    const int nwaves = gridDim.x * WPB;

    const int      k    = pk[0];
    const uint32_t flip = (plg[0] != 0) ? 0u : 0xFFFFFFFFu;

    int row = wave;
    if (row >= rows) return;

    // prologue: load first row (element e=j*4+c at row idx j*256+lane*4+c)
    uint4v pre[NV];
    {
        const uint4v* xr = (const uint4v*)(x + (size_t)row * C);
        #pragma unroll
        for (int j = 0; j < NV; ++j) pre[j] = xr[j * 64 + lane];
    }

    for (; row < rows; row += nwaves) {
        // ---- keys for current row (consumes pre) --------------------------
        uint32_t key[EPL];
        #pragma unroll
        for (int j = 0; j < NV; ++j) {
            #pragma unroll
            for (int c2 = 0; c2 < 4; ++c2)
                key[j*4+c2] = f2key(pre[j][c2], flip);
        }
        // ---- prefetch next row: in flight during the search ---------------
        const int nxt = row + nwaves;
        if (nxt < rows) {
            const uint4v* xn = (const uint4v*)(x + (size_t)nxt * C);
            #pragma unroll
            for (int j = 0; j < NV; ++j) pre[j] = xn[j * 64 + lane];
        }

        float4v* orow = (float4v*)(out + (size_t)row * C);

        if (k <= 0) {
            const float4v z = {0.f, 0.f, 0.f, 0.f};
            #pragma unroll
            for (int j = 0; j < NV; ++j) orow[j * 64 + lane] = z;
            continue;
        }
        if (k >= C) {   // select everything
            #pragma unroll
            for (int j = 0; j < NV; ++j) {
                float4v o;
                #pragma unroll
                for (int c2 = 0; c2 < 4; ++c2) o[c2] = key2f(key[j*4+c2], flip);
                orow[j * 64 + lane] = o;
            }
            continue;
        }

        // ---- bitwise binary search for T = k-th largest key ---------------
        // Invariant: count(key >= T) >= k. Final T = k-th largest key.
        uint32_t T = 0;
        bool exact = false;
        for (int b = 31; b >= 0; --b) {
            const uint32_t cand = T | (1u << b);
            int cnt = 0;
            #pragma unroll
            for (int e = 0; e < EPL; ++e)
                cnt += __popcll(__ballot(key[e] >= cand));
            if (cnt >= k) {
                T = cand;
                if (cnt == k) { exact = true; break; }
            }
        }

        // ---- selection mask ----------------------------------------------
        uint32_t selmask = 0;
        if (exact) {
            #pragma unroll
            for (int e = 0; e < EPL; ++e)
                if (key[e] >= T) selmask |= 1u << e;
        } else {
            // duplicates of T straddle the boundary: take (k - count(>T)) of
            // the keys == T, lowest row-index first. Index order = (j,lane,c).
            int cgt = 0;
            #pragma unroll
            for (int e = 0; e < EPL; ++e) {
                if (key[e] > T) selmask |= 1u << e;
                cgt += __popcll(__ballot(key[e] > T));
            }
            const int need = k - cgt;  // >= 1 by construction
            const unsigned long long below = (1ull << lane) - 1ull;
            int base = 0;
            #pragma unroll
            for (int j = 0; j < NV; ++j) {
                int eq[4]; unsigned long long m[4];
                #pragma unroll
                for (int c2 = 0; c2 < 4; ++c2) {
                    eq[c2] = (key[j*4+c2] == T) ? 1 : 0;
                    m[c2]  = __ballot(eq[c2] != 0);
                }
                int lanebelow = 0;
                #pragma unroll
                for (int c2 = 0; c2 < 4; ++c2) lanebelow += __popcll(m[c2] & below);
                int own = 0;
                #pragma unroll
                for (int c2 = 0; c2 < 4; ++c2) {
                    if (eq[c2] && (base + lanebelow + own) < need)
                        selmask |= 1u << (j*4 + c2);
                    own += eq[c2];
                }
                #pragma unroll
                for (int c2 = 0; c2 < 4; ++c2) base += __popcll(m[c2]);
            }
        }

        // ---- scatter values / zeros (coalesced 16B stores) ----------------
        #pragma unroll
        for (int j = 0; j < NV; ++j) {
            float4v o;
            #pragma unroll
            for (int c2 = 0; c2 < 4; ++c2) {
                const int e = j*4 + c2;
                o[c2] = ((selmask >> e) & 1u) ? key2f(key[e], flip) : 0.0f;
            }
            orow[j * 64 + lane] = o;
        }
    }
}

extern "C" void kernel_launch(void* const* d_in, const int* in_sizes, int n_in,
                              void* d_out, int out_size, void* d_ws, size_t ws_size,
                              hipStream_t stream) {
    const float* x   = (const float*)d_in[0];
    const int*   pk  = (const int*)d_in[1];
    const int*   plg = (const int*)d_in[2];
    float*       out = (float*)d_out;

    const int rows   = in_sizes[0] / C;   // 16*4096 = 65536
    const int blocks = 4096;              // 16384 waves -> 4 rows/wave grid-stride
    topk_scatter_row<<<blocks, TPB, 0, stream>>>(x, pk, plg, out, rows);
}